// Round 1
// baseline (340.943 us; speedup 1.0000x reference)
//
#include <hip/hip_runtime.h>

#define DIM 64
#define LSTRIDE 68              // bf16 elems per row: 64 + 4 pad -> 34 dwords (2-way bank alias = free)
#define PLANE (DIM * LSTRIDE)   // 4352 ushorts = 8704 B per plane

typedef __attribute__((ext_vector_type(8))) short short8;
typedef __attribute__((ext_vector_type(16))) float f32x16;

#define MFMA(a, b, c) __builtin_amdgcn_mfma_f32_32x32x16_bf16((a), (b), (c), 0, 0, 0)

__device__ __forceinline__ unsigned short f2bf(float v) {
    unsigned int u = __float_as_uint(v);
    unsigned int r = (u + 0x7fffu + ((u >> 16) & 1u)) >> 16;  // RNE
    return (unsigned short)r;
}
__device__ __forceinline__ float bf2f(unsigned short h) {
    return __uint_as_float(((unsigned int)h) << 16);
}

union FragU { short8 v; uint2 u2[2]; };

__device__ __forceinline__ short8 load_frag(const unsigned short* p) {
    // 8 contiguous bf16 (16 B) at an 8-byte-aligned LDS address -> 2x ds_read_b64
    FragU f;
    f.u2[0] = *(const uint2*)p;
    f.u2[1] = *(const uint2*)(p + 4);
    return f.v;
}

// planes: 0 Wh, 1 Wl (A / ZY / P), 2 Yh, 3 Yl, 4 Zh, 5 Zl
extern "C" __global__ void __launch_bounds__(256, 3)
isqrtm_kernel(const float* __restrict__ x, const int* __restrict__ iterN_p,
              float* __restrict__ out)
{
    __shared__ __align__(16) unsigned short pl[6][PLANE];
    __shared__ float s_tr;

    const int t = threadIdx.x;
    const int b = blockIdx.x;
    const float* xg = x + (size_t)b * 4096;
    float* og = out + (size_t)b * 4096;
    const int iterN = iterN_p[0];

    // ---- trace (normA) : wave 0 reduces the diagonal ----
    if (t < 64) {
        float v = xg[t * 65];
        #pragma unroll
        for (int o = 32; o > 0; o >>= 1) v += __shfl_down(v, o);
        if (t == 0) s_tr = v;
    }
    __syncthreads();
    const float tr  = s_tr;
    const float inv = 1.0f / tr;
    const float sc  = sqrtf(tr);

    // ---- build A (W planes) and Z = ZY0 = 1.5I - 0.5A ----
    #pragma unroll
    for (int ch = 0; ch < 4; ++ch) {
        const int e  = ch * 1024 + t * 4;
        const int i  = e >> 6, j0 = e & 63;
        const float4 xv = *(const float4*)(xg + e);
        float av[4] = { xv.x * inv, xv.y * inv, xv.z * inv, xv.w * inv };
        unsigned short ah[4], al[4], zh[4], zl[4];
        #pragma unroll
        for (int q = 0; q < 4; ++q) {
            const float a = av[q];
            const unsigned short h = f2bf(a);
            ah[q] = h; al[q] = f2bf(a - bf2f(h));
            const float z = ((i == j0 + q) ? 1.5f : 0.0f) - 0.5f * a;
            const unsigned short hz = f2bf(z);
            zh[q] = hz; zl[q] = f2bf(z - bf2f(hz));
        }
        const int ad = i * LSTRIDE + j0;
        *(ushort4*)&pl[0][ad] = make_ushort4(ah[0], ah[1], ah[2], ah[3]);
        *(ushort4*)&pl[1][ad] = make_ushort4(al[0], al[1], al[2], al[3]);
        *(ushort4*)&pl[4][ad] = make_ushort4(zh[0], zh[1], zh[2], zh[3]);
        *(ushort4*)&pl[5][ad] = make_ushort4(zl[0], zl[1], zl[2], zl[3]);
    }
    __syncthreads();

    // ---- wave / tile constants ----
    const int lane = t & 63;
    const int wv = t >> 6;
    const int wr = wv >> 1, wc = wv & 1;        // 32x32 tile coords
    const int m  = lane & 31, hh = lane >> 5;
    // fragment row offset: row = 32*blk + m, k0 = 16*s + 8*hh  (A and B identical by symmetry)
    const int ra = (32 * wr + m) * LSTRIDE + 8 * hh;
    const int rb = (32 * wc + m) * LSTRIDE + 8 * hh;

    // C = M1(A-op, row-block wr) @ M2(B-op, col-block wc), hi/lo 3-term
    auto matmul = [&](int a_, int b_) -> f32x16 {
        f32x16 acc = {};
        #pragma unroll
        for (int s = 0; s < 4; ++s) {
            const short8 ah = load_frag(&pl[a_][ra + 16 * s]);
            const short8 al = load_frag(&pl[a_ + 1][ra + 16 * s]);
            const short8 bh = load_frag(&pl[b_][rb + 16 * s]);
            const short8 bl = load_frag(&pl[b_ + 1][rb + 16 * s]);
            acc = MFMA(ah, bh, acc);
            acc = MFMA(ah, bl, acc);
            acc = MFMA(al, bh, acc);
        }
        return acc;
    };

    // two products sharing the A-operand (W): o1 = W@M1, o2 = W@M2
    auto matmul2 = [&](int b1_, int b2_, f32x16& o1, f32x16& o2) {
        o1 = {}; o2 = {};
        #pragma unroll
        for (int s = 0; s < 4; ++s) {
            const short8 ah  = load_frag(&pl[0][ra + 16 * s]);
            const short8 al  = load_frag(&pl[1][ra + 16 * s]);
            const short8 b1h = load_frag(&pl[b1_][rb + 16 * s]);
            const short8 b1l = load_frag(&pl[b1_ + 1][rb + 16 * s]);
            const short8 b2h = load_frag(&pl[b2_][rb + 16 * s]);
            const short8 b2l = load_frag(&pl[b2_ + 1][rb + 16 * s]);
            o1 = MFMA(ah, b1h, o1); o1 = MFMA(ah, b1l, o1); o1 = MFMA(al, b1h, o1);
            o2 = MFMA(ah, b2h, o2); o2 = MFMA(ah, b2l, o2); o2 = MFMA(al, b2h, o2);
        }
    };

    // write C-layout tile into a plane pair, transposed (valid: result symmetric).
    // zyform: v <- 1.5*(row==col) - 0.5*v
    auto write_tile = [&](int p_, const f32x16& acc, bool zyform) {
        #pragma unroll
        for (int g = 0; g < 4; ++g) {
            unsigned short h4[4], l4[4];
            #pragma unroll
            for (int q = 0; q < 4; ++q) {
                const int rl = q + 8 * g + 4 * hh;       // local row in tile
                float v = acc[4 * g + q];
                if (zyform) {
                    const int grow = 32 * wr + rl, gcol = 32 * wc + m;
                    v = ((grow == gcol) ? 1.5f : 0.0f) - 0.5f * v;
                }
                const unsigned short hv = f2bf(v);
                h4[q] = hv;
                l4[q] = f2bf(v - bf2f(hv));
            }
            const int ad = (32 * wc + m) * LSTRIDE + (32 * wr + 8 * g + 4 * hh);
            *(ushort4*)&pl[p_][ad]     = make_ushort4(h4[0], h4[1], h4[2], h4[3]);
            *(ushort4*)&pl[p_ + 1][ad] = make_ushort4(l4[0], l4[1], l4[2], l4[3]);
        }
    };

    auto write_global = [&](const f32x16& acc, float scale) {
        #pragma unroll
        for (int g = 0; g < 4; ++g)
            #pragma unroll
            for (int q = 0; q < 4; ++q) {
                const int rl = q + 8 * g + 4 * hh;
                og[(32 * wr + rl) * 64 + 32 * wc + m] = acc[4 * g + q] * scale;
            }
    };

    // ---- step 1: Y1 = A @ ZY0  (W as A-op, Z as B-op) ----
    {
        const f32x16 accY = matmul(0, 4);
        if (iterN < 2) { write_global(accY, sc); return; }
        write_tile(2, accY, false);              // Y planes
    }
    __syncthreads();

    // ---- loop: 3 matmuls / iteration ----
    for (int it = 1; it < iterN - 1; ++it) {
        const f32x16 T = matmul(4, 2);           // Z @ Y   (reads Z,Y; writes W: safe)
        write_tile(0, T, true);                  // W = 0.5*(3I - T)
        __syncthreads();
        f32x16 nY, nZ;
        matmul2(2, 4, nY, nZ);                   // nY = ZY@Y (=Y@ZY), nZ = ZY@Z
        __syncthreads();                         // all reads of Y,Z done
        write_tile(2, nY, false);
        write_tile(4, nZ, false);
        __syncthreads();
    }

    // ---- final: YZY = 0.5 * Y @ (3I - Z@Y), y = YZY * sqrt(normA) ----
    {
        const f32x16 T = matmul(4, 2);           // Z @ Y
        write_tile(0, T, true);                  // W = P = 0.5*(3I - Z@Y)
        __syncthreads();
        const f32x16 O = matmul(0, 2);           // P @ Y (= Y @ P)
        write_global(O, sc);
    }
}

extern "C" void kernel_launch(void* const* d_in, const int* in_sizes, int n_in,
                              void* d_out, int out_size, void* d_ws, size_t ws_size,
                              hipStream_t stream) {
    const float* x = (const float*)d_in[0];
    const int* iterN = (const int*)d_in[1];
    float* out = (float*)d_out;
    const int B = in_sizes[0] / (DIM * DIM);   // 8192
    isqrtm_kernel<<<dim3(B), dim3(256), 0, stream>>>(x, iterN, out);
}

// Round 2
// 321.844 us; speedup vs baseline: 1.0593x; 1.0593x over previous
//
#include <hip/hip_runtime.h>

#define DIM 64
#define LSTRIDE 68              // bf16 elems per row: 64 + 4 pad -> 34 dwords (2-way bank alias = free)
#define PLANE (DIM * LSTRIDE)   // 4352 ushorts = 8704 B per plane

typedef __attribute__((ext_vector_type(8))) short short8;
typedef __attribute__((ext_vector_type(16))) float f32x16;

#define MFMA(a, b, c) __builtin_amdgcn_mfma_f32_32x32x16_bf16((a), (b), (c), 0, 0, 0)

// hi = round-half-up bf16 (kept as high-aligned dword), lo = v - hi (exact in fp32)
__device__ __forceinline__ void split_hl(float v, unsigned int& uh, unsigned int& ul) {
    unsigned int u = __float_as_uint(v);
    uh = (u + 0x8000u) & 0xffff0000u;          // 2 VALU
    float lo = v - __uint_as_float(uh);        // 1 VALU, exact (<=17 sig bits)
    ul = __float_as_uint(lo);                  // lo stored truncated -> err 2^-19 * v
}

union FragU { short8 v; uint2 u2[2]; };

__device__ __forceinline__ short8 load_frag(const unsigned short* p) {
    FragU f;
    f.u2[0] = *(const uint2*)p;
    f.u2[1] = *(const uint2*)(p + 4);
    return f.v;
}

// planes: 0 Wh, 1 Wl (A / ZY / P), 2 Yh, 3 Yl, 4 Zh, 5 Zl
extern "C" __global__ void __launch_bounds__(256, 3)
isqrtm_kernel(const float* __restrict__ x, const int* __restrict__ iterN_p,
              float* __restrict__ out)
{
    __shared__ __align__(16) unsigned short pl[6][PLANE];
    __shared__ float s_tr;

    const int t = threadIdx.x;
    const int b = blockIdx.x;
    const float* xg = x + (size_t)b * 4096;
    float* og = out + (size_t)b * 4096;
    const int iterN = iterN_p[0];

    // ---- trace (normA) : wave 0 reduces the diagonal ----
    if (t < 64) {
        float v = xg[t * 65];
        #pragma unroll
        for (int o = 32; o > 0; o >>= 1) v += __shfl_down(v, o);
        if (t == 0) s_tr = v;
    }
    __syncthreads();
    const float tr  = s_tr;
    const float inv = 1.0f / tr;
    const float sc  = sqrtf(tr);

    // ---- build A (W planes) and Z = ZY0 = 1.5I - 0.5A ----
    #pragma unroll
    for (int ch = 0; ch < 4; ++ch) {
        const int e  = ch * 1024 + t * 4;
        const int i  = e >> 6, j0 = e & 63;
        const float4 xv = *(const float4*)(xg + e);
        const float av[4] = { xv.x * inv, xv.y * inv, xv.z * inv, xv.w * inv };
        unsigned int ahu[4], alu[4], zhu[4], zlu[4];
        #pragma unroll
        for (int q = 0; q < 4; ++q) {
            split_hl(av[q], ahu[q], alu[q]);
            const float z = fmaf(-0.5f, av[q], (i == j0 + q) ? 1.5f : 0.0f);
            split_hl(z, zhu[q], zlu[q]);
        }
        const int ad = i * LSTRIDE + j0;
        *(uint2*)&pl[0][ad] = make_uint2((ahu[0] >> 16) | ahu[1], (ahu[2] >> 16) | ahu[3]);
        *(uint2*)&pl[1][ad] = make_uint2((alu[0] >> 16) | (alu[1] & 0xffff0000u),
                                         (alu[2] >> 16) | (alu[3] & 0xffff0000u));
        *(uint2*)&pl[4][ad] = make_uint2((zhu[0] >> 16) | zhu[1], (zhu[2] >> 16) | zhu[3]);
        *(uint2*)&pl[5][ad] = make_uint2((zlu[0] >> 16) | (zlu[1] & 0xffff0000u),
                                         (zlu[2] >> 16) | (zlu[3] & 0xffff0000u));
    }
    __syncthreads();

    // ---- wave / tile constants ----
    const int lane = t & 63;
    const int wv = t >> 6;
    const int wr = wv >> 1, wc = wv & 1;        // 32x32 tile coords
    const int m  = lane & 31, hh = lane >> 5;
    const int ra = (32 * wr + m) * LSTRIDE + 8 * hh;
    const int rb = (32 * wc + m) * LSTRIDE + 8 * hh;
    const int dql = 32 * wc + m - 32 * wr - 4 * hh;   // diag test: q + 8g == dql

    short8 yh[4], yl[4];                        // cached B-op fragments (Y)

    auto load_B = [&](int p_) {
        #pragma unroll
        for (int s = 0; s < 4; ++s) {
            yh[s] = load_frag(&pl[p_][rb + 16 * s]);
            yl[s] = load_frag(&pl[p_ + 1][rb + 16 * s]);
        }
    };

    // C = M(a_) @ Ycached, hi/lo 3-term
    auto matmul_cB = [&](int a_) -> f32x16 {
        f32x16 acc = {};
        #pragma unroll
        for (int s = 0; s < 4; ++s) {
            const short8 ah = load_frag(&pl[a_][ra + 16 * s]);
            const short8 al = load_frag(&pl[a_ + 1][ra + 16 * s]);
            acc = MFMA(ah, yh[s], acc);
            acc = MFMA(ah, yl[s], acc);
            acc = MFMA(al, yh[s], acc);
        }
        return acc;
    };

    // o1 = W @ Ycached, o2 = W @ M(b2_)  (shared W A-fragments)
    auto matmul2_cB = [&](int b2_, f32x16& o1, f32x16& o2) {
        o1 = {}; o2 = {};
        #pragma unroll
        for (int s = 0; s < 4; ++s) {
            const short8 ah  = load_frag(&pl[0][ra + 16 * s]);
            const short8 al  = load_frag(&pl[1][ra + 16 * s]);
            const short8 b2h = load_frag(&pl[b2_][rb + 16 * s]);
            const short8 b2l = load_frag(&pl[b2_ + 1][rb + 16 * s]);
            o1 = MFMA(ah, yh[s], o1); o1 = MFMA(ah, yl[s], o1); o1 = MFMA(al, yh[s], o1);
            o2 = MFMA(ah, b2h, o2);   o2 = MFMA(ah, b2l, o2);   o2 = MFMA(al, b2h, o2);
        }
    };

    // write C-layout tile into a plane pair, transposed (valid: result symmetric).
    auto write_tile = [&](int p_, const f32x16& acc, bool zyform) {
        #pragma unroll
        for (int g = 0; g < 4; ++g) {
            unsigned int uh[4], ul[4];
            #pragma unroll
            for (int q = 0; q < 4; ++q) {
                float v = acc[4 * g + q];
                if (zyform)
                    v = fmaf(-0.5f, v, (q + 8 * g == dql) ? 1.5f : 0.0f);
                split_hl(v, uh[q], ul[q]);
            }
            const int ad = (32 * wc + m) * LSTRIDE + (32 * wr + 8 * g + 4 * hh);
            *(uint2*)&pl[p_][ad]     = make_uint2((uh[0] >> 16) | uh[1], (uh[2] >> 16) | uh[3]);
            *(uint2*)&pl[p_ + 1][ad] = make_uint2((ul[0] >> 16) | (ul[1] & 0xffff0000u),
                                                  (ul[2] >> 16) | (ul[3] & 0xffff0000u));
        }
    };

    auto write_global = [&](const f32x16& acc, float scale) {
        #pragma unroll
        for (int g = 0; g < 4; ++g)
            #pragma unroll
            for (int q = 0; q < 4; ++q) {
                const int rl = q + 8 * g + 4 * hh;
                og[(32 * wr + rl) * 64 + 32 * wc + m] = acc[4 * g + q] * scale;
            }
    };

    // ---- step 1: Y1 = A @ ZY0  (W as A-op, Z cached as B-op) ----
    {
        load_B(4);
        const f32x16 accY = matmul_cB(0);
        if (iterN < 2) { write_global(accY, sc); return; }
        write_tile(2, accY, false);              // Y planes
    }
    __syncthreads();

    // ---- loop: 3 matmuls / iteration, Y B-frags cached across both ----
    for (int it = 1; it < iterN - 1; ++it) {
        load_B(2);                               // Y as B-op (valid: post-sync)
        const f32x16 T = matmul_cB(4);           // Z @ Y
        write_tile(0, T, true);                  // W = 0.5*(3I - T)
        __syncthreads();
        f32x16 nY, nZ;
        matmul2_cB(4, nY, nZ);                   // nY = W@Y (=Y@ZY), nZ = W@Z
        __syncthreads();                         // all reads of Y,Z done
        write_tile(2, nY, false);
        write_tile(4, nZ, false);
        __syncthreads();
    }

    // ---- final: YZY = 0.5 * Y @ (3I - Z@Y), y = YZY * sqrt(normA) ----
    {
        load_B(2);                               // Y cached for both matmuls
        const f32x16 T = matmul_cB(4);           // Z @ Y
        write_tile(0, T, true);                  // W = P = 0.5*(3I - Z@Y)
        __syncthreads();
        const f32x16 O = matmul_cB(0);           // P @ Y (= Y @ P)
        write_global(O, sc);
    }
}

extern "C" void kernel_launch(void* const* d_in, const int* in_sizes, int n_in,
                              void* d_out, int out_size, void* d_ws, size_t ws_size,
                              hipStream_t stream) {
    const float* x = (const float*)d_in[0];
    const int* iterN = (const int*)d_in[1];
    float* out = (float*)d_out;
    const int B = in_sizes[0] / (DIM * DIM);   // 8192
    isqrtm_kernel<<<dim3(B), dim3(256), 0, stream>>>(x, iterN, out);
}